// Round 1
// baseline (5255.764 us; speedup 1.0000x reference)
//
#include <hip/hip_runtime.h>

// ---------------------------------------------------------------------------
// JointlyTrainModel: 4x ChebConv(K=3) dense-block GNN + 3-layer MLP head w/ BN.
// Graph = 2048 identical 62-node graphs (block-diagonal), so L~ is ONE 62x62
// sparse matrix. fp32 throughout (round 0: correctness + baseline profile).
// ---------------------------------------------------------------------------

#define NODES   62
#define BATCH   2048
#define NTOT    (NODES * BATCH)     // 126976
#define IN_DIM  128
#define OUT_DIM 62
#define XCOLS   376                 // 128 + 4*62
#define LIN1    512
#define LIN2    256
#define NCLS    3
#define BN_EPS  1e-5f

// ---------------------------------------------------------------------------
// Build CSR of L~ = -D^{-1/2} A D^{-1/2} from graph 0's edges (all graphs share
// topology; duplicate edges accumulate exactly like segment_sum in the ref).
// ---------------------------------------------------------------------------
__global__ __launch_bounds__(256) void build_L(
    const int* __restrict__ ei, int E, int epg,
    int* __restrict__ rp, int* __restrict__ ci, float* __restrict__ cv)
{
    __shared__ float Ls[NODES * NODES];
    __shared__ int   deg[NODES];
    __shared__ float dinv[NODES];
    const int t = threadIdx.x;
    for (int i = t; i < NODES * NODES; i += 256) Ls[i] = 0.f;
    if (t < NODES) deg[t] = 0;
    __syncthreads();
    const int* row = ei;
    const int* col = ei + E;
    for (int j = t; j < epg; j += 256) atomicAdd(&deg[row[j]], 1);
    __syncthreads();
    if (t < NODES) dinv[t] = (deg[t] > 0) ? rsqrtf((float)deg[t]) : 0.f;
    __syncthreads();
    for (int j = t; j < epg; j += 256) {
        int r = row[j], c = col[j];
        atomicAdd(&Ls[r * NODES + c], -dinv[r] * dinv[c]);
    }
    __syncthreads();
    if (t == 0) {  // tiny serial CSR compaction (62x62)
        int p = 0;
        for (int r = 0; r < NODES; ++r) {
            rp[r] = p;
            for (int c = 0; c < NODES; ++c) {
                float v = Ls[r * NODES + c];
                if (v != 0.f) { ci[p] = c; cv[p] = v; ++p; }
            }
        }
        rp[NODES] = p;
    }
}

// ---------------------------------------------------------------------------
// Copy x [N,128] into X[:, 0:128] (row stride 376), float4 vectorized.
// ---------------------------------------------------------------------------
__global__ __launch_bounds__(256) void scatter_x(
    const float4* __restrict__ x4, float* __restrict__ X)
{
    int idx = blockIdx.x * 256 + threadIdx.x;     // over NTOT*32
    if (idx < NTOT * 32) {
        int r = idx >> 5, f4 = idx & 31;
        *(float4*)&X[(size_t)r * XCOLS + f4 * 4] = x4[idx];
    }
}

#define ACC16(av, bv) do {                              \
    acc[0][0] = fmaf((av).x, (bv).x, acc[0][0]);        \
    acc[0][1] = fmaf((av).x, (bv).y, acc[0][1]);        \
    acc[0][2] = fmaf((av).x, (bv).z, acc[0][2]);        \
    acc[0][3] = fmaf((av).x, (bv).w, acc[0][3]);        \
    acc[1][0] = fmaf((av).y, (bv).x, acc[1][0]);        \
    acc[1][1] = fmaf((av).y, (bv).y, acc[1][1]);        \
    acc[1][2] = fmaf((av).y, (bv).z, acc[1][2]);        \
    acc[1][3] = fmaf((av).y, (bv).w, acc[1][3]);        \
    acc[2][0] = fmaf((av).z, (bv).x, acc[2][0]);        \
    acc[2][1] = fmaf((av).z, (bv).y, acc[2][1]);        \
    acc[2][2] = fmaf((av).z, (bv).z, acc[2][2]);        \
    acc[2][3] = fmaf((av).z, (bv).w, acc[2][3]);        \
    acc[3][0] = fmaf((av).w, (bv).x, acc[3][0]);        \
    acc[3][1] = fmaf((av).w, (bv).y, acc[3][1]);        \
    acc[3][2] = fmaf((av).w, (bv).z, acc[3][2]);        \
    acc[3][3] = fmaf((av).w, (bv).w, acc[3][3]);        \
} while (0)

// ---------------------------------------------------------------------------
// Fused Cheb layer: block = one graph. For each 16-col chunk f0 of the input:
//   t1 = L~ @ h_chunk, t2 = 2 L~ @ t1 - h_chunk  (CSR, in LDS)
//   acc += h@W0 + t1@W1 + t2@W2 for this chunk.
// Epilogue: Xout[:, d : d+62] = relu(acc + bias).
// A tiles stored transposed [kt][row] stride 72 so the 4x4 register tile
// reads are ds_read_b128.
// ---------------------------------------------------------------------------
__global__ __launch_bounds__(256) void cheb_layer(
    const float* __restrict__ X, float* __restrict__ Xout,
    const float* __restrict__ W, const float* __restrict__ bias,
    const int* __restrict__ rp, const int* __restrict__ ci,
    const float* __restrict__ cv, int d)
{
    __shared__ __align__(16) float hs [16 * 72];
    __shared__ __align__(16) float t1s[16 * 72];
    __shared__ __align__(16) float t2s[16 * 72];
    __shared__ __align__(16) float Bs [3 * 16 * 64];
    __shared__ int   rp_s[NODES + 1];
    __shared__ int   ci_s[512];
    __shared__ float cv_s[512];

    const int tid = threadIdx.x;
    const int g   = blockIdx.x;
    const int ty4 = (tid >> 4) * 4;
    const int tx4 = (tid & 15) * 4;

    if (tid < NODES + 1) rp_s[tid] = rp[tid];
    for (int i = tid; i < 496; i += 256) { ci_s[i] = ci[i]; cv_s[i] = cv[i]; }
    // zero pad rows 62..71 once (never rewritten; feeds discarded acc rows)
    for (int i = tid; i < 16 * 72; i += 256) {
        if ((i % 72) >= NODES) { hs[i] = 0.f; t1s[i] = 0.f; t2s[i] = 0.f; }
    }

    float acc[4][4] = {};
    const int nchunk = (d + 15) >> 4;
    for (int ch = 0; ch < nchunk; ++ch) {
        const int f0 = ch << 4;
        // stage h chunk (transposed) + all three B tiles
        for (int i = tid; i < NODES * 16; i += 256) {
            int r = i >> 4, f = i & 15;
            int gf = f0 + f;
            hs[f * 72 + r] = (gf < d) ? X[(size_t)(g * NODES + r) * XCOLS + gf] : 0.f;
        }
        for (int i = tid; i < 3 * 16 * 64; i += 256) {
            int seg = i >> 10;
            int kt  = (i >> 6) & 15;
            int c   = i & 63;
            int kk  = f0 + kt;
            Bs[i] = (kk < d && c < OUT_DIM) ? W[(size_t)(seg * d + kk) * OUT_DIM + c] : 0.f;
        }
        __syncthreads();
        // t1 = L~ @ h
        for (int o = tid; o < NODES * 16; o += 256) {
            int r = o >> 4, f = o & 15;
            float s = 0.f;
            int e1 = rp_s[r + 1];
            for (int e = rp_s[r]; e < e1; ++e) s += cv_s[e] * hs[f * 72 + ci_s[e]];
            t1s[f * 72 + r] = s;
        }
        __syncthreads();
        // t2 = 2 L~ @ t1 - h
        for (int o = tid; o < NODES * 16; o += 256) {
            int r = o >> 4, f = o & 15;
            float s = 0.f;
            int e1 = rp_s[r + 1];
            for (int e = rp_s[r]; e < e1; ++e) s += cv_s[e] * t1s[f * 72 + ci_s[e]];
            t2s[f * 72 + r] = 2.f * s - hs[f * 72 + r];
        }
        __syncthreads();
        // acc += [h | t1 | t2] @ [W0; W1; W2] for this chunk
        #pragma unroll
        for (int kt = 0; kt < 16; ++kt) {
            const float4 av = *(const float4*)&hs[kt * 72 + ty4];
            const float4 bv = *(const float4*)&Bs[0 * 1024 + kt * 64 + tx4];
            ACC16(av, bv);
        }
        #pragma unroll
        for (int kt = 0; kt < 16; ++kt) {
            const float4 av = *(const float4*)&t1s[kt * 72 + ty4];
            const float4 bv = *(const float4*)&Bs[1 * 1024 + kt * 64 + tx4];
            ACC16(av, bv);
        }
        #pragma unroll
        for (int kt = 0; kt < 16; ++kt) {
            const float4 av = *(const float4*)&t2s[kt * 72 + ty4];
            const float4 bv = *(const float4*)&Bs[2 * 1024 + kt * 64 + tx4];
            ACC16(av, bv);
        }
        __syncthreads();
    }
    // epilogue: relu(acc + bias) into X[:, d : d+62]
    #pragma unroll
    for (int i = 0; i < 4; ++i) {
        int r = ty4 + i;
        if (r < NODES) {
            #pragma unroll
            for (int j = 0; j < 4; ++j) {
                int c = tx4 + j;
                if (c < OUT_DIM)
                    Xout[(size_t)(g * NODES + r) * XCOLS + d + c] =
                        fmaxf(acc[i][j] + bias[c], 0.f);
            }
        }
    }
}

// ---------------------------------------------------------------------------
// Head GEMM1: H1[2048,512] = feats[2048,15376] @ Wh1 + bh1.
// feats[b, m] = X[(b*62 + m/248)*376 + 128 + m%248]. K = 961*16 exactly.
// 64x64 tile, 4x4 per thread, KT=16.
// ---------------------------------------------------------------------------
__global__ __launch_bounds__(256) void gemm_head1(
    const float* __restrict__ X, const float* __restrict__ Wh1,
    const float* __restrict__ bh1, float* __restrict__ H1)
{
    __shared__ __align__(16) float As[16 * 72];
    __shared__ __align__(16) float Bs[16 * 64];
    const int bm = blockIdx.x;      // 0..31
    const int bn = blockIdx.y;      // 0..7
    const int tid = threadIdx.x;
    const int ty4 = (tid >> 4) * 4;
    const int tx4 = (tid & 15) * 4;
    float acc[4][4] = {};
    for (int k0 = 0; k0 < 15376; k0 += 16) {
        for (int i = tid; i < 1024; i += 256) {
            int m = i >> 4, kt = i & 15;
            int k = k0 + kt;
            int node = k / 248;
            int j = k - node * 248;
            int b = bm * 64 + m;
            As[kt * 72 + m] = X[(size_t)(b * NODES + node) * XCOLS + IN_DIM + j];
        }
        for (int i = tid; i < 1024; i += 256) {
            int kt = i >> 6, c = i & 63;
            Bs[kt * 64 + c] = Wh1[(size_t)(k0 + kt) * LIN1 + bn * 64 + c];
        }
        __syncthreads();
        #pragma unroll
        for (int kt = 0; kt < 16; ++kt) {
            const float4 av = *(const float4*)&As[kt * 72 + ty4];
            const float4 bv = *(const float4*)&Bs[kt * 64 + tx4];
            ACC16(av, bv);
        }
        __syncthreads();
    }
    const int b = bm * 64 + ty4, c = bn * 64 + tx4;
    #pragma unroll
    for (int i = 0; i < 4; ++i) {
        float4 o;
        o.x = acc[i][0] + bh1[c + 0];
        o.y = acc[i][1] + bh1[c + 1];
        o.z = acc[i][2] + bh1[c + 2];
        o.w = acc[i][3] + bh1[c + 3];
        *(float4*)&H1[(size_t)(b + i) * LIN1 + c] = o;
    }
}

// ---------------------------------------------------------------------------
// GEMM2: H2[2048,256] = H1[2048,512] @ Wh2 + bh2.
// ---------------------------------------------------------------------------
__global__ __launch_bounds__(256) void gemm2_kernel(
    const float* __restrict__ A, const float* __restrict__ B,
    const float* __restrict__ bias, float* __restrict__ C)
{
    __shared__ __align__(16) float As[16 * 72];
    __shared__ __align__(16) float Bs[16 * 64];
    const int bm = blockIdx.x;      // 0..31
    const int bn = blockIdx.y;      // 0..3
    const int tid = threadIdx.x;
    const int ty4 = (tid >> 4) * 4;
    const int tx4 = (tid & 15) * 4;
    float acc[4][4] = {};
    for (int k0 = 0; k0 < LIN1; k0 += 16) {
        for (int i = tid; i < 1024; i += 256) {
            int m = i >> 4, kt = i & 15;
            As[kt * 72 + m] = A[(size_t)(bm * 64 + m) * LIN1 + k0 + kt];
        }
        for (int i = tid; i < 1024; i += 256) {
            int kt = i >> 6, c = i & 63;
            Bs[kt * 64 + c] = B[(size_t)(k0 + kt) * LIN2 + bn * 64 + c];
        }
        __syncthreads();
        #pragma unroll
        for (int kt = 0; kt < 16; ++kt) {
            const float4 av = *(const float4*)&As[kt * 72 + ty4];
            const float4 bv = *(const float4*)&Bs[kt * 64 + tx4];
            ACC16(av, bv);
        }
        __syncthreads();
    }
    const int b = bm * 64 + ty4, c = bn * 64 + tx4;
    #pragma unroll
    for (int i = 0; i < 4; ++i) {
        float4 o;
        o.x = acc[i][0] + bias[c + 0];
        o.y = acc[i][1] + bias[c + 1];
        o.z = acc[i][2] + bias[c + 2];
        o.w = acc[i][3] + bias[c + 3];
        *(float4*)&C[(size_t)(b + i) * LIN2 + c] = o;
    }
}

// ---------------------------------------------------------------------------
// BatchNorm (training stats, biased var) + ReLU, in place. Block covers 16
// columns; 16 row-threads x 16 col-threads for coalesced-ish access.
// ---------------------------------------------------------------------------
__global__ __launch_bounds__(256) void bn_relu_kernel(
    float* __restrict__ H, int C,
    const float* __restrict__ gamma, const float* __restrict__ beta)
{
    const int c  = blockIdx.x * 16 + (threadIdx.x & 15);
    const int rt = threadIdx.x >> 4;
    const int ct = threadIdx.x & 15;
    float s = 0.f, s2 = 0.f;
    for (int r = rt; r < BATCH; r += 16) {
        float v = H[(size_t)r * C + c];
        s += v; s2 += v * v;
    }
    __shared__ float Ss[16][16], S2s[16][16], sc_s[16], sh_s[16];
    Ss[rt][ct] = s; S2s[rt][ct] = s2;
    __syncthreads();
    if (rt == 0) {
        float ts = 0.f, ts2 = 0.f;
        #pragma unroll
        for (int i = 0; i < 16; ++i) { ts += Ss[i][ct]; ts2 += S2s[i][ct]; }
        float m   = ts * (1.f / BATCH);
        float var = ts2 * (1.f / BATCH) - m * m;
        float sc  = gamma[c] * rsqrtf(var + BN_EPS);
        sc_s[ct] = sc;
        sh_s[ct] = beta[c] - m * sc;
    }
    __syncthreads();
    const float sc = sc_s[ct], sh = sh_s[ct];
    for (int r = rt; r < BATCH; r += 16) {
        float v = H[(size_t)r * C + c];
        H[(size_t)r * C + c] = fmaxf(fmaf(v, sc, sh), 0.f);
    }
}

// ---------------------------------------------------------------------------
// Final: logits = H2 @ Wh3 + bh3, softmax over 3 classes.
// ---------------------------------------------------------------------------
__global__ __launch_bounds__(256) void final_kernel(
    const float* __restrict__ H2, const float* __restrict__ Wh3,
    const float* __restrict__ bh3, float* __restrict__ out)
{
    __shared__ float Ws[LIN2 * NCLS];
    __shared__ float bs[NCLS];
    const int tid = threadIdx.x;
    for (int i = tid; i < LIN2 * NCLS; i += 256) Ws[i] = Wh3[i];
    if (tid < NCLS) bs[tid] = bh3[tid];
    __syncthreads();
    const int r = blockIdx.x * 256 + tid;   // 8*256 = 2048 rows
    float a0 = bs[0], a1 = bs[1], a2 = bs[2];
    const float4* row = (const float4*)&H2[(size_t)r * LIN2];
    for (int k4 = 0; k4 < LIN2 / 4; ++k4) {
        float4 h = row[k4];
        int k = k4 * 4;
        a0 = fmaf(h.x, Ws[(k + 0) * 3 + 0], a0);
        a1 = fmaf(h.x, Ws[(k + 0) * 3 + 1], a1);
        a2 = fmaf(h.x, Ws[(k + 0) * 3 + 2], a2);
        a0 = fmaf(h.y, Ws[(k + 1) * 3 + 0], a0);
        a1 = fmaf(h.y, Ws[(k + 1) * 3 + 1], a1);
        a2 = fmaf(h.y, Ws[(k + 1) * 3 + 2], a2);
        a0 = fmaf(h.z, Ws[(k + 2) * 3 + 0], a0);
        a1 = fmaf(h.z, Ws[(k + 2) * 3 + 1], a1);
        a2 = fmaf(h.z, Ws[(k + 2) * 3 + 2], a2);
        a0 = fmaf(h.w, Ws[(k + 3) * 3 + 0], a0);
        a1 = fmaf(h.w, Ws[(k + 3) * 3 + 1], a1);
        a2 = fmaf(h.w, Ws[(k + 3) * 3 + 2], a2);
    }
    float mx = fmaxf(a0, fmaxf(a1, a2));
    float e0 = expf(a0 - mx), e1 = expf(a1 - mx), e2 = expf(a2 - mx);
    float inv = 1.f / (e0 + e1 + e2);
    out[r * 3 + 0] = e0 * inv;
    out[r * 3 + 1] = e1 * inv;
    out[r * 3 + 2] = e2 * inv;
}

// ---------------------------------------------------------------------------
extern "C" void kernel_launch(void* const* d_in, const int* in_sizes, int n_in,
                              void* d_out, int out_size, void* d_ws, size_t ws_size,
                              hipStream_t stream)
{
    const float* x   = (const float*)d_in[0];
    const int*   ei  = (const int*)  d_in[1];
    const float* W1  = (const float*)d_in[2];
    const float* b1  = (const float*)d_in[3];
    const float* W2  = (const float*)d_in[4];
    const float* b2  = (const float*)d_in[5];
    const float* W3  = (const float*)d_in[6];
    const float* b3  = (const float*)d_in[7];
    const float* W4  = (const float*)d_in[8];
    const float* b4  = (const float*)d_in[9];
    const float* Wh1 = (const float*)d_in[10];
    const float* bh1 = (const float*)d_in[11];
    const float* g1  = (const float*)d_in[12];
    const float* be1 = (const float*)d_in[13];
    const float* Wh2 = (const float*)d_in[14];
    const float* bh2 = (const float*)d_in[15];
    const float* g2  = (const float*)d_in[16];
    const float* be2 = (const float*)d_in[17];
    const float* Wh3 = (const float*)d_in[18];
    const float* bh3 = (const float*)d_in[19];
    float* out = (float*)d_out;

    // workspace layout (all 256B-aligned):
    //   [0)      rp (63 ints)
    //   [1024)   ci (496 ints)
    //   [4096)   cv (496 floats)
    //   [8192)   X  [N, 376] fp32        = 190,971,904 B
    //   [..]     H1 [2048, 512] fp32     =   4,194,304 B
    //   [..]     H2 [2048, 256] fp32     =   2,097,152 B   (total ~188 MiB)
    char* ws = (char*)d_ws;
    int*   rp = (int*)(ws + 0);
    int*   ci = (int*)(ws + 1024);
    float* cv = (float*)(ws + 4096);
    float* X  = (float*)(ws + 8192);
    size_t xbytes = (size_t)NTOT * XCOLS * sizeof(float);
    float* H1 = (float*)(ws + 8192 + xbytes);
    float* H2 = (float*)(ws + 8192 + xbytes + (size_t)BATCH * LIN1 * sizeof(float));

    const int E   = in_sizes[1] / 2;   // 1,015,808
    const int epg = E / BATCH;         // 496 edges of graph 0

    build_L<<<1, 256, 0, stream>>>(ei, E, epg, rp, ci, cv);
    scatter_x<<<(NTOT * 32 + 255) / 256, 256, 0, stream>>>((const float4*)x, X);

    cheb_layer<<<BATCH, 256, 0, stream>>>(X, X, W1, b1, rp, ci, cv, 128);
    cheb_layer<<<BATCH, 256, 0, stream>>>(X, X, W2, b2, rp, ci, cv, 190);
    cheb_layer<<<BATCH, 256, 0, stream>>>(X, X, W3, b3, rp, ci, cv, 252);
    cheb_layer<<<BATCH, 256, 0, stream>>>(X, X, W4, b4, rp, ci, cv, 314);

    gemm_head1<<<dim3(32, 8), 256, 0, stream>>>(X, Wh1, bh1, H1);
    bn_relu_kernel<<<LIN1 / 16, 256, 0, stream>>>(H1, LIN1, g1, be1);
    gemm2_kernel<<<dim3(32, 4), 256, 0, stream>>>(H1, Wh2, bh2, H2);
    bn_relu_kernel<<<LIN2 / 16, 256, 0, stream>>>(H2, LIN2, g2, be2);
    final_kernel<<<BATCH / 256, 256, 0, stream>>>(H2, Wh3, bh3, out);
}

// Round 2
// 3407.972 us; speedup vs baseline: 1.5422x; 1.5422x over previous
//
#include <hip/hip_runtime.h>

// ---------------------------------------------------------------------------
// JointlyTrainModel: 4x ChebConv(K=3) dense-block GNN + 3-layer MLP head w/ BN.
// Round 2: split-K on head GEMMs (R1 showed gemm_head1 at 3010us with 1
// block/CU, VALUBusy 10.5% -- latency-bound). LDS stride 72->80 (2-way bank
// aliasing = free) everywhere.
// ---------------------------------------------------------------------------

#define NODES   62
#define BATCH   2048
#define NTOT    (NODES * BATCH)     // 126976
#define IN_DIM  128
#define OUT_DIM 62
#define XCOLS   376                 // 128 + 4*62
#define LIN1    512
#define LIN2    256
#define NCLS    3
#define BN_EPS  1e-5f
#define ASTRIDE 80                  // LDS A-tile stride: bank step 16 -> 2-way (free)

// ---------------------------------------------------------------------------
// Build CSR of L~ = -D^{-1/2} A D^{-1/2} from graph 0's edges (all graphs share
// topology; duplicate edges accumulate exactly like segment_sum in the ref).
// ---------------------------------------------------------------------------
__global__ __launch_bounds__(256) void build_L(
    const int* __restrict__ ei, int E, int epg,
    int* __restrict__ rp, int* __restrict__ ci, float* __restrict__ cv)
{
    __shared__ float Ls[NODES * NODES];
    __shared__ int   deg[NODES];
    __shared__ float dinv[NODES];
    const int t = threadIdx.x;
    for (int i = t; i < NODES * NODES; i += 256) Ls[i] = 0.f;
    if (t < NODES) deg[t] = 0;
    __syncthreads();
    const int* row = ei;
    const int* col = ei + E;
    for (int j = t; j < epg; j += 256) atomicAdd(&deg[row[j]], 1);
    __syncthreads();
    if (t < NODES) dinv[t] = (deg[t] > 0) ? rsqrtf((float)deg[t]) : 0.f;
    __syncthreads();
    for (int j = t; j < epg; j += 256) {
        int r = row[j], c = col[j];
        atomicAdd(&Ls[r * NODES + c], -dinv[r] * dinv[c]);
    }
    __syncthreads();
    if (t == 0) {  // tiny serial CSR compaction (62x62)
        int p = 0;
        for (int r = 0; r < NODES; ++r) {
            rp[r] = p;
            for (int c = 0; c < NODES; ++c) {
                float v = Ls[r * NODES + c];
                if (v != 0.f) { ci[p] = c; cv[p] = v; ++p; }
            }
        }
        rp[NODES] = p;
    }
}

// ---------------------------------------------------------------------------
// Copy x [N,128] into X[:, 0:128] (row stride 376), float4 vectorized.
// ---------------------------------------------------------------------------
__global__ __launch_bounds__(256) void scatter_x(
    const float4* __restrict__ x4, float* __restrict__ X)
{
    int idx = blockIdx.x * 256 + threadIdx.x;     // over NTOT*32
    if (idx < NTOT * 32) {
        int r = idx >> 5, f4 = idx & 31;
        *(float4*)&X[(size_t)r * XCOLS + f4 * 4] = x4[idx];
    }
}

// H[b, 0:C] = bias[0:C] broadcast (pre-init for split-K atomic accumulation).
__global__ __launch_bounds__(256) void init_bias(
    float* __restrict__ H, const float* __restrict__ bias, int c4mask, int total4)
{
    int i = blockIdx.x * 256 + threadIdx.x;
    if (i < total4)
        ((float4*)H)[i] = ((const float4*)bias)[i & c4mask];
}

#define ACC16(av, bv) do {                              \
    acc[0][0] = fmaf((av).x, (bv).x, acc[0][0]);        \
    acc[0][1] = fmaf((av).x, (bv).y, acc[0][1]);        \
    acc[0][2] = fmaf((av).x, (bv).z, acc[0][2]);        \
    acc[0][3] = fmaf((av).x, (bv).w, acc[0][3]);        \
    acc[1][0] = fmaf((av).y, (bv).x, acc[1][0]);        \
    acc[1][1] = fmaf((av).y, (bv).y, acc[1][1]);        \
    acc[1][2] = fmaf((av).y, (bv).z, acc[1][2]);        \
    acc[1][3] = fmaf((av).y, (bv).w, acc[1][3]);        \
    acc[2][0] = fmaf((av).z, (bv).x, acc[2][0]);        \
    acc[2][1] = fmaf((av).z, (bv).y, acc[2][1]);        \
    acc[2][2] = fmaf((av).z, (bv).z, acc[2][2]);        \
    acc[2][3] = fmaf((av).z, (bv).w, acc[2][3]);        \
    acc[3][0] = fmaf((av).w, (bv).x, acc[3][0]);        \
    acc[3][1] = fmaf((av).w, (bv).y, acc[3][1]);        \
    acc[3][2] = fmaf((av).w, (bv).z, acc[3][2]);        \
    acc[3][3] = fmaf((av).w, (bv).w, acc[3][3]);        \
} while (0)

// ---------------------------------------------------------------------------
// Fused Cheb layer: block = one graph (2048 blocks). See round-1 comments.
// ---------------------------------------------------------------------------
__global__ __launch_bounds__(256) void cheb_layer(
    const float* __restrict__ X, float* __restrict__ Xout,
    const float* __restrict__ W, const float* __restrict__ bias,
    const int* __restrict__ rp, const int* __restrict__ ci,
    const float* __restrict__ cv, int d)
{
    __shared__ __align__(16) float hs [16 * ASTRIDE];
    __shared__ __align__(16) float t1s[16 * ASTRIDE];
    __shared__ __align__(16) float t2s[16 * ASTRIDE];
    __shared__ __align__(16) float Bs [3 * 16 * 64];
    __shared__ int   rp_s[NODES + 1];
    __shared__ int   ci_s[512];
    __shared__ float cv_s[512];

    const int tid = threadIdx.x;
    const int g   = blockIdx.x;
    const int ty4 = (tid >> 4) * 4;
    const int tx4 = (tid & 15) * 4;

    if (tid < NODES + 1) rp_s[tid] = rp[tid];
    for (int i = tid; i < 496; i += 256) { ci_s[i] = ci[i]; cv_s[i] = cv[i]; }
    // zero pad rows 62..79 once (never rewritten; feeds discarded acc rows)
    for (int i = tid; i < 16 * ASTRIDE; i += 256) {
        if ((i % ASTRIDE) >= NODES) { hs[i] = 0.f; t1s[i] = 0.f; t2s[i] = 0.f; }
    }

    float acc[4][4] = {};
    const int nchunk = (d + 15) >> 4;
    for (int ch = 0; ch < nchunk; ++ch) {
        const int f0 = ch << 4;
        for (int i = tid; i < NODES * 16; i += 256) {
            int r = i >> 4, f = i & 15;
            int gf = f0 + f;
            hs[f * ASTRIDE + r] = (gf < d) ? X[(size_t)(g * NODES + r) * XCOLS + gf] : 0.f;
        }
        for (int i = tid; i < 3 * 16 * 64; i += 256) {
            int seg = i >> 10;
            int kt  = (i >> 6) & 15;
            int c   = i & 63;
            int kk  = f0 + kt;
            Bs[i] = (kk < d && c < OUT_DIM) ? W[(size_t)(seg * d + kk) * OUT_DIM + c] : 0.f;
        }
        __syncthreads();
        for (int o = tid; o < NODES * 16; o += 256) {
            int r = o >> 4, f = o & 15;
            float s = 0.f;
            int e1 = rp_s[r + 1];
            for (int e = rp_s[r]; e < e1; ++e) s += cv_s[e] * hs[f * ASTRIDE + ci_s[e]];
            t1s[f * ASTRIDE + r] = s;
        }
        __syncthreads();
        for (int o = tid; o < NODES * 16; o += 256) {
            int r = o >> 4, f = o & 15;
            float s = 0.f;
            int e1 = rp_s[r + 1];
            for (int e = rp_s[r]; e < e1; ++e) s += cv_s[e] * t1s[f * ASTRIDE + ci_s[e]];
            t2s[f * ASTRIDE + r] = 2.f * s - hs[f * ASTRIDE + r];
        }
        __syncthreads();
        #pragma unroll
        for (int kt = 0; kt < 16; ++kt) {
            const float4 av = *(const float4*)&hs[kt * ASTRIDE + ty4];
            const float4 bv = *(const float4*)&Bs[0 * 1024 + kt * 64 + tx4];
            ACC16(av, bv);
        }
        #pragma unroll
        for (int kt = 0; kt < 16; ++kt) {
            const float4 av = *(const float4*)&t1s[kt * ASTRIDE + ty4];
            const float4 bv = *(const float4*)&Bs[1 * 1024 + kt * 64 + tx4];
            ACC16(av, bv);
        }
        #pragma unroll
        for (int kt = 0; kt < 16; ++kt) {
            const float4 av = *(const float4*)&t2s[kt * ASTRIDE + ty4];
            const float4 bv = *(const float4*)&Bs[2 * 1024 + kt * 64 + tx4];
            ACC16(av, bv);
        }
        __syncthreads();
    }
    #pragma unroll
    for (int i = 0; i < 4; ++i) {
        int r = ty4 + i;
        if (r < NODES) {
            #pragma unroll
            for (int j = 0; j < 4; ++j) {
                int c = tx4 + j;
                if (c < OUT_DIM)
                    Xout[(size_t)(g * NODES + r) * XCOLS + d + c] =
                        fmaxf(acc[i][j] + bias[c], 0.f);
            }
        }
    }
}

// ---------------------------------------------------------------------------
// Head GEMM1 (split-K): H1 += feats[2048,15376] @ Wh1, split over blockIdx.z.
// Grid (32, 8, SPLIT1) = 2048 blocks -> 8 blocks/CU. H1 pre-init'd to bias.
// ---------------------------------------------------------------------------
#define SPLIT1 8
__global__ __launch_bounds__(256) void gemm_head1(
    const float* __restrict__ X, const float* __restrict__ Wh1,
    float* __restrict__ H1)
{
    __shared__ __align__(16) float As[16 * ASTRIDE];
    __shared__ __align__(16) float Bs[16 * 64];
    const int bm = blockIdx.x;      // 0..31
    const int bn = blockIdx.y;      // 0..7
    const int s  = blockIdx.z;      // 0..SPLIT1-1
    const int tid = threadIdx.x;
    const int ty4 = (tid >> 4) * 4;
    const int tx4 = (tid & 15) * 4;
    const int k16s = (961 * s) / SPLIT1;
    const int k16e = (961 * (s + 1)) / SPLIT1;
    float acc[4][4] = {};
    for (int k16 = k16s; k16 < k16e; ++k16) {
        const int k0 = k16 * 16;
        for (int i = tid; i < 1024; i += 256) {
            int m = i >> 4, kt = i & 15;
            int k = k0 + kt;
            int node = k / 248;
            int j = k - node * 248;
            int b = bm * 64 + m;
            As[kt * ASTRIDE + m] = X[(size_t)(b * NODES + node) * XCOLS + IN_DIM + j];
        }
        for (int i = tid; i < 1024; i += 256) {
            int kt = i >> 6, c = i & 63;
            Bs[kt * 64 + c] = Wh1[(size_t)(k0 + kt) * LIN1 + bn * 64 + c];
        }
        __syncthreads();
        #pragma unroll
        for (int kt = 0; kt < 16; ++kt) {
            const float4 av = *(const float4*)&As[kt * ASTRIDE + ty4];
            const float4 bv = *(const float4*)&Bs[kt * 64 + tx4];
            ACC16(av, bv);
        }
        __syncthreads();
    }
    const int b = bm * 64 + ty4, c = bn * 64 + tx4;
    #pragma unroll
    for (int i = 0; i < 4; ++i)
        #pragma unroll
        for (int j = 0; j < 4; ++j)
            atomicAdd(&H1[(size_t)(b + i) * LIN1 + c + j], acc[i][j]);
}

// ---------------------------------------------------------------------------
// GEMM2 (split-K): H2 += H1[2048,512] @ Wh2. Grid (32,4,SPLIT2) = 512 blocks.
// ---------------------------------------------------------------------------
#define SPLIT2 4
__global__ __launch_bounds__(256) void gemm2_kernel(
    const float* __restrict__ A, const float* __restrict__ B,
    float* __restrict__ C)
{
    __shared__ __align__(16) float As[16 * ASTRIDE];
    __shared__ __align__(16) float Bs[16 * 64];
    const int bm = blockIdx.x;      // 0..31
    const int bn = blockIdx.y;      // 0..3
    const int s  = blockIdx.z;      // 0..SPLIT2-1
    const int tid = threadIdx.x;
    const int ty4 = (tid >> 4) * 4;
    const int tx4 = (tid & 15) * 4;
    const int kbeg = s * (LIN1 / SPLIT2);
    const int kend = kbeg + LIN1 / SPLIT2;
    float acc[4][4] = {};
    for (int k0 = kbeg; k0 < kend; k0 += 16) {
        for (int i = tid; i < 1024; i += 256) {
            int m = i >> 4, kt = i & 15;
            As[kt * ASTRIDE + m] = A[(size_t)(bm * 64 + m) * LIN1 + k0 + kt];
        }
        for (int i = tid; i < 1024; i += 256) {
            int kt = i >> 6, c = i & 63;
            Bs[kt * 64 + c] = B[(size_t)(k0 + kt) * LIN2 + bn * 64 + c];
        }
        __syncthreads();
        #pragma unroll
        for (int kt = 0; kt < 16; ++kt) {
            const float4 av = *(const float4*)&As[kt * ASTRIDE + ty4];
            const float4 bv = *(const float4*)&Bs[kt * 64 + tx4];
            ACC16(av, bv);
        }
        __syncthreads();
    }
    const int b = bm * 64 + ty4, c = bn * 64 + tx4;
    #pragma unroll
    for (int i = 0; i < 4; ++i)
        #pragma unroll
        for (int j = 0; j < 4; ++j)
            atomicAdd(&C[(size_t)(b + i) * LIN2 + c + j], acc[i][j]);
}

// ---------------------------------------------------------------------------
// BatchNorm (training stats, biased var) + ReLU, in place.
// ---------------------------------------------------------------------------
__global__ __launch_bounds__(256) void bn_relu_kernel(
    float* __restrict__ H, int C,
    const float* __restrict__ gamma, const float* __restrict__ beta)
{
    const int c  = blockIdx.x * 16 + (threadIdx.x & 15);
    const int rt = threadIdx.x >> 4;
    const int ct = threadIdx.x & 15;
    float s = 0.f, s2 = 0.f;
    for (int r = rt; r < BATCH; r += 16) {
        float v = H[(size_t)r * C + c];
        s += v; s2 += v * v;
    }
    __shared__ float Ss[16][16], S2s[16][16], sc_s[16], sh_s[16];
    Ss[rt][ct] = s; S2s[rt][ct] = s2;
    __syncthreads();
    if (rt == 0) {
        float ts = 0.f, ts2 = 0.f;
        #pragma unroll
        for (int i = 0; i < 16; ++i) { ts += Ss[i][ct]; ts2 += S2s[i][ct]; }
        float m   = ts * (1.f / BATCH);
        float var = ts2 * (1.f / BATCH) - m * m;
        float sc  = gamma[c] * rsqrtf(var + BN_EPS);
        sc_s[ct] = sc;
        sh_s[ct] = beta[c] - m * sc;
    }
    __syncthreads();
    const float sc = sc_s[ct], sh = sh_s[ct];
    for (int r = rt; r < BATCH; r += 16) {
        float v = H[(size_t)r * C + c];
        H[(size_t)r * C + c] = fmaxf(fmaf(v, sc, sh), 0.f);
    }
}

// ---------------------------------------------------------------------------
// Final: logits = H2 @ Wh3 + bh3, softmax over 3 classes.
// ---------------------------------------------------------------------------
__global__ __launch_bounds__(256) void final_kernel(
    const float* __restrict__ H2, const float* __restrict__ Wh3,
    const float* __restrict__ bh3, float* __restrict__ out)
{
    __shared__ float Ws[LIN2 * NCLS];
    __shared__ float bs[NCLS];
    const int tid = threadIdx.x;
    for (int i = tid; i < LIN2 * NCLS; i += 256) Ws[i] = Wh3[i];
    if (tid < NCLS) bs[tid] = bh3[tid];
    __syncthreads();
    const int r = blockIdx.x * 256 + tid;
    float a0 = bs[0], a1 = bs[1], a2 = bs[2];
    const float4* row = (const float4*)&H2[(size_t)r * LIN2];
    for (int k4 = 0; k4 < LIN2 / 4; ++k4) {
        float4 h = row[k4];
        int k = k4 * 4;
        a0 = fmaf(h.x, Ws[(k + 0) * 3 + 0], a0);
        a1 = fmaf(h.x, Ws[(k + 0) * 3 + 1], a1);
        a2 = fmaf(h.x, Ws[(k + 0) * 3 + 2], a2);
        a0 = fmaf(h.y, Ws[(k + 1) * 3 + 0], a0);
        a1 = fmaf(h.y, Ws[(k + 1) * 3 + 1], a1);
        a2 = fmaf(h.y, Ws[(k + 1) * 3 + 2], a2);
        a0 = fmaf(h.z, Ws[(k + 2) * 3 + 0], a0);
        a1 = fmaf(h.z, Ws[(k + 2) * 3 + 1], a1);
        a2 = fmaf(h.z, Ws[(k + 2) * 3 + 2], a2);
        a0 = fmaf(h.w, Ws[(k + 3) * 3 + 0], a0);
        a1 = fmaf(h.w, Ws[(k + 3) * 3 + 1], a1);
        a2 = fmaf(h.w, Ws[(k + 3) * 3 + 2], a2);
    }
    float mx = fmaxf(a0, fmaxf(a1, a2));
    float e0 = expf(a0 - mx), e1 = expf(a1 - mx), e2 = expf(a2 - mx);
    float inv = 1.f / (e0 + e1 + e2);
    out[r * 3 + 0] = e0 * inv;
    out[r * 3 + 1] = e1 * inv;
    out[r * 3 + 2] = e2 * inv;
}

// ---------------------------------------------------------------------------
extern "C" void kernel_launch(void* const* d_in, const int* in_sizes, int n_in,
                              void* d_out, int out_size, void* d_ws, size_t ws_size,
                              hipStream_t stream)
{
    const float* x   = (const float*)d_in[0];
    const int*   ei  = (const int*)  d_in[1];
    const float* W1  = (const float*)d_in[2];
    const float* b1  = (const float*)d_in[3];
    const float* W2  = (const float*)d_in[4];
    const float* b2  = (const float*)d_in[5];
    const float* W3  = (const float*)d_in[6];
    const float* b3  = (const float*)d_in[7];
    const float* W4  = (const float*)d_in[8];
    const float* b4  = (const float*)d_in[9];
    const float* Wh1 = (const float*)d_in[10];
    const float* bh1 = (const float*)d_in[11];
    const float* g1  = (const float*)d_in[12];
    const float* be1 = (const float*)d_in[13];
    const float* Wh2 = (const float*)d_in[14];
    const float* bh2 = (const float*)d_in[15];
    const float* g2  = (const float*)d_in[16];
    const float* be2 = (const float*)d_in[17];
    const float* Wh3 = (const float*)d_in[18];
    const float* bh3 = (const float*)d_in[19];
    float* out = (float*)d_out;

    char* ws = (char*)d_ws;
    int*   rp = (int*)(ws + 0);
    int*   ci = (int*)(ws + 1024);
    float* cv = (float*)(ws + 4096);
    float* X  = (float*)(ws + 8192);
    size_t xbytes = (size_t)NTOT * XCOLS * sizeof(float);
    float* H1 = (float*)(ws + 8192 + xbytes);
    float* H2 = (float*)(ws + 8192 + xbytes + (size_t)BATCH * LIN1 * sizeof(float));

    const int E   = in_sizes[1] / 2;   // 1,015,808
    const int epg = E / BATCH;         // 496 edges of graph 0

    build_L<<<1, 256, 0, stream>>>(ei, E, epg, rp, ci, cv);
    scatter_x<<<(NTOT * 32 + 255) / 256, 256, 0, stream>>>((const float4*)x, X);

    cheb_layer<<<BATCH, 256, 0, stream>>>(X, X, W1, b1, rp, ci, cv, 128);
    cheb_layer<<<BATCH, 256, 0, stream>>>(X, X, W2, b2, rp, ci, cv, 190);
    cheb_layer<<<BATCH, 256, 0, stream>>>(X, X, W3, b3, rp, ci, cv, 252);
    cheb_layer<<<BATCH, 256, 0, stream>>>(X, X, W4, b4, rp, ci, cv, 314);

    // H1 = bias; H1 += feats @ Wh1 (split-K, atomic)
    init_bias<<<(BATCH * LIN1 / 4 + 255) / 256, 256, 0, stream>>>(H1, bh1, LIN1 / 4 - 1, BATCH * LIN1 / 4);
    gemm_head1<<<dim3(32, 8, SPLIT1), 256, 0, stream>>>(X, Wh1, H1);
    bn_relu_kernel<<<LIN1 / 16, 256, 0, stream>>>(H1, LIN1, g1, be1);

    init_bias<<<(BATCH * LIN2 / 4 + 255) / 256, 256, 0, stream>>>(H2, bh2, LIN2 / 4 - 1, BATCH * LIN2 / 4);
    gemm2_kernel<<<dim3(32, 4, SPLIT2), 256, 0, stream>>>(H1, Wh2, H2);
    bn_relu_kernel<<<LIN2 / 16, 256, 0, stream>>>(H2, LIN2, g2, be2);

    final_kernel<<<BATCH / 256, 256, 0, stream>>>(H2, Wh3, bh3, out);
}

// Round 4
// 2108.039 us; speedup vs baseline: 2.4932x; 1.6167x over previous
//
#include <hip/hip_runtime.h>

// ---------------------------------------------------------------------------
// JointlyTrainModel round 4: R3 (bf16 MFMA) with workspace shrunk 264->149 MB.
// R3 crashed: layout overran ws (likely 256 MiB). Changes:
//  - activations stored as X248[N][248] fp32 only (feats rows contiguous!)
//  - cheb input cols <128 read directly from d_in[0]
//  - no bf16 feats shadow; head GEMM1 converts fp32->bf16 while staging
// ---------------------------------------------------------------------------

#define NODES   62
#define BATCH   2048
#define NTOT    (NODES * BATCH)     // 126976
#define IN_DIM  128
#define OUT_DIM 62
#define ACOLS   248                 // 4*62 activation cols
#define FEAT    15376               // 62*248
#define LIN1    512
#define LIN2    256
#define NCLS    3
#define BN_EPS  1e-5f
#define ELLW    24
#define DSTR    66                  // fp32 LDS col-major stride (floats)
#define BSTR    40                  // bf16 LDS row stride (ushorts) = 80B rows

typedef __attribute__((ext_vector_type(8))) short   short8;
typedef __attribute__((ext_vector_type(4))) float   f32x4;

__device__ inline unsigned short f2bf(float x) {
    unsigned u = __builtin_bit_cast(unsigned, x);
    return (unsigned short)((u + 0x7fffu + ((u >> 16) & 1u)) >> 16);
}
__device__ inline float bf2f(unsigned short h) {
    return __builtin_bit_cast(float, (unsigned)h << 16);
}

// ---------------------------------------------------------------------------
// Build ELL(24) of L~ = -D^{-1/2} A D^{-1/2} from graph 0's edges.
// Layout [j][64 rows]; rows 62,63 and pad entries are (ci=0, cv=0).
// ---------------------------------------------------------------------------
__global__ __launch_bounds__(64) void build_L(
    const int* __restrict__ ei, int E, int epg,
    int* __restrict__ ell_ci, float* __restrict__ ell_cv)
{
    __shared__ float Ls[NODES * NODES];
    __shared__ int   deg[NODES];
    __shared__ float dinv[NODES];
    const int t = threadIdx.x;
    for (int i = t; i < NODES * NODES; i += 64) Ls[i] = 0.f;
    if (t < NODES) deg[t] = 0;
    __syncthreads();
    const int* row = ei;
    const int* col = ei + E;
    for (int j = t; j < epg; j += 64) atomicAdd(&deg[row[j]], 1);
    __syncthreads();
    if (t < NODES) dinv[t] = (deg[t] > 0) ? rsqrtf((float)deg[t]) : 0.f;
    __syncthreads();
    for (int j = t; j < epg; j += 64) {
        int r = row[j], c = col[j];
        atomicAdd(&Ls[r * NODES + c], -dinv[r] * dinv[c]);
    }
    __syncthreads();
    int cnt = 0;
    if (t < NODES) {
        for (int c = 0; c < NODES; ++c) {
            float v = Ls[t * NODES + c];
            if (v != 0.f && cnt < ELLW) {
                ell_ci[cnt * 64 + t] = c;
                ell_cv[cnt * 64 + t] = v;
                ++cnt;
            }
        }
    }
    for (int j = cnt; j < ELLW; ++j) {
        ell_ci[j * 64 + t] = 0;
        ell_cv[j * 64 + t] = 0.f;
    }
}

// H[b, 0:C] = bias broadcast (pre-init for split-K atomic accumulation).
__global__ __launch_bounds__(256) void init_bias(
    float* __restrict__ H, const float* __restrict__ bias, int c4mask, int total4)
{
    int i = blockIdx.x * 256 + threadIdx.x;
    if (i < total4)
        ((float4*)H)[i] = ((const float4*)bias)[i & c4mask];
}

// ---------------------------------------------------------------------------
// Cheb weight conversion: W[3][d][62] fp32 -> WT hi/lo planes, transposed +
// zero-padded: WT[plane][n<64][kcat<3*dpad], kcat = seg*dpad + kk.
// ---------------------------------------------------------------------------
__global__ __launch_bounds__(256) void conv_wcheb(
    const float* __restrict__ W, unsigned short* __restrict__ WT, int d, int dpad)
{
    const int Kcat = 3 * dpad;
    int idx = blockIdx.x * 256 + threadIdx.x;
    if (idx >= 64 * Kcat) return;
    int n = idx / Kcat, kcat = idx - n * Kcat;
    int seg = kcat / dpad, kk = kcat - seg * dpad;
    float v = (n < NODES && kk < d) ? W[((size_t)seg * d + kk) * OUT_DIM + n] : 0.f;
    unsigned short hi = f2bf(v);
    unsigned short lo = f2bf(v - bf2f(hi));
    WT[idx] = hi;
    WT[(size_t)64 * Kcat + idx] = lo;
}

// ---------------------------------------------------------------------------
// Wh1 [15376][512] fp32 -> Wh1T [512][15376] bf16, via LDS 32x32 transpose.
// ---------------------------------------------------------------------------
__global__ __launch_bounds__(256) void transpose_wh1(
    const float* __restrict__ W, unsigned short* __restrict__ WT)
{
    __shared__ float T[32][33];
    const int k0 = blockIdx.x * 32, n0 = blockIdx.y * 32;
    {
        int kl = threadIdx.x >> 3, n4 = (threadIdx.x & 7) * 4;
        if (k0 + kl < FEAT) {
            float4 v = *(const float4*)&W[(size_t)(k0 + kl) * LIN1 + n0 + n4];
            T[kl][n4] = v.x; T[kl][n4 + 1] = v.y; T[kl][n4 + 2] = v.z; T[kl][n4 + 3] = v.w;
        }
    }
    __syncthreads();
    {
        int nl = threadIdx.x >> 3, k4 = (threadIdx.x & 7) * 4;
        if (k0 + k4 + 3 < FEAT) {
            ushort4 o;
            o.x = f2bf(T[k4 + 0][nl]);
            o.y = f2bf(T[k4 + 1][nl]);
            o.z = f2bf(T[k4 + 2][nl]);
            o.w = f2bf(T[k4 + 3][nl]);
            *(ushort4*)&WT[(size_t)(n0 + nl) * FEAT + k0 + k4] = o;
        }
    }
}

// ---------------------------------------------------------------------------
// Fused Cheb layer, MFMA. Block = one graph (2048 blocks, 256 thr).
// Input cols < 128 come from x (d_in), cols >= 128 from X248. The chunk width
// 32 divides 128, so the source select is chunk-uniform.
// Per 32-col chunk: stage h fp32, t1 = L~h (ELL); per segment: hi/lo bf16
// convert to A-fragment layout + stage B hi/lo; 16x16x32 MFMA, 3 products.
// Epilogue: relu(acc + bias) -> X248[:, d-128 : d-128+62].
// ---------------------------------------------------------------------------
__global__ __launch_bounds__(256) void cheb_mfma(
    const float* __restrict__ x, float* __restrict__ X248,
    const unsigned short* __restrict__ WT, const float* __restrict__ bias,
    const int* __restrict__ ell_ci, const float* __restrict__ ell_cv,
    int d, int dpad)
{
    __shared__ float hs [32 * DSTR];
    __shared__ float t1s[32 * DSTR];
    __shared__ __align__(16) unsigned short A16[2][64 * BSTR];
    __shared__ __align__(16) unsigned short B16[2][64 * BSTR];
    __shared__ float cv_s[ELLW * 64];
    __shared__ int   ci_s[ELLW * 64];
    __shared__ float bias_s[64];

    const int tid  = threadIdx.x;
    const int g    = blockIdx.x;
    const int lane = tid & 63;
    const int wv   = tid >> 6;        // wave id = m-tile
    const int fcol = tid & 31;        // staging/prop col
    const int rrow = tid >> 5;        // staging/prop row base (0..7)
    const int Kcat = 3 * dpad;

    for (int i = tid; i < ELLW * 64; i += 256) { ci_s[i] = ell_ci[i]; cv_s[i] = ell_cv[i]; }
    if (tid < 64) bias_s[tid] = (tid < OUT_DIM) ? bias[tid] : 0.f;

    f32x4 acc[4];
    acc[0] = (f32x4){0.f, 0.f, 0.f, 0.f};
    acc[1] = (f32x4){0.f, 0.f, 0.f, 0.f};
    acc[2] = (f32x4){0.f, 0.f, 0.f, 0.f};
    acc[3] = (f32x4){0.f, 0.f, 0.f, 0.f};

    const int cm  = tid & 63;         // conversion row
    const int ckg = (tid >> 6) * 8;   // conversion k-group
    const int bn  = tid >> 2;         // B-stage row
    const int bkg = (tid & 3) * 8;    // B-stage k-group

    for (int kk0 = 0; kk0 < dpad; kk0 += 32) {
        // stage h chunk fp32, col-major [f][r] stride DSTR
        {
            const int gf = kk0 + fcol;
            const bool fromx = (kk0 < IN_DIM);   // chunk-uniform
            #pragma unroll
            for (int p = 0; p < 8; ++p) {
                int r = p * 8 + rrow;
                float v = 0.f;
                if (r < NODES && gf < d)
                    v = fromx ? x[(size_t)(g * NODES + r) * IN_DIM + gf]
                              : X248[(size_t)(g * NODES + r) * ACOLS + (gf - IN_DIM)];
                hs[fcol * DSTR + r] = v;
            }
        }
        __syncthreads();
        // t1 = L~ h   (rows >= 62 get 0: cv padded with 0)
        #pragma unroll
        for (int p = 0; p < 8; ++p) {
            int r = p * 8 + rrow;
            float s = 0.f;
            #pragma unroll
            for (int j = 0; j < ELLW; ++j)
                s += cv_s[j * 64 + r] * hs[fcol * DSTR + ci_s[j * 64 + r]];
            t1s[fcol * DSTR + r] = s;
        }
        __syncthreads();

        for (int seg = 0; seg < 3; ++seg) {
            // --- convert A chunk to hi/lo bf16, row-major [m][k] stride BSTR
            {
                short8 vh, vl;
                #pragma unroll
                for (int j = 0; j < 8; ++j) {
                    int k = ckg + j;
                    float xv;
                    if (seg == 0)      xv = hs[k * DSTR + cm];
                    else if (seg == 1) xv = t1s[k * DSTR + cm];
                    else {
                        float s = 0.f;
                        #pragma unroll
                        for (int e = 0; e < ELLW; ++e)
                            s += cv_s[e * 64 + cm] * t1s[k * DSTR + ci_s[e * 64 + cm]];
                        xv = 2.f * s - hs[k * DSTR + cm];
                    }
                    unsigned short h = f2bf(xv);
                    vh[j] = (short)h;
                    vl[j] = (short)f2bf(xv - bf2f(h));
                }
                *(short8*)&A16[0][cm * BSTR + ckg] = vh;
                *(short8*)&A16[1][cm * BSTR + ckg] = vl;
            }
            // --- stage B hi/lo from WT (pre-transposed/padded)
            {
                const unsigned short* src = WT + (size_t)bn * Kcat + seg * dpad + kk0 + bkg;
                *(short8*)&B16[0][bn * BSTR + bkg] = *(const short8*)src;
                *(short8*)&B16[1][bn * BSTR + bkg] = *(const short8*)(src + (size_t)64 * Kcat);
            }
            __syncthreads();
            // --- MFMA sweep: wave wv owns m-tile wv, all 4 n-tiles
            {
                const int aoff = (wv * 16 + (lane & 15)) * BSTR + (lane >> 4) * 8;
                short8 ahi = *(short8*)&A16[0][aoff];
                short8 alo = *(short8*)&A16[1][aoff];
                #pragma unroll
                for (int nt = 0; nt < 4; ++nt) {
                    const int boff = (nt * 16 + (lane & 15)) * BSTR + (lane >> 4) * 8;
                    short8 bhi = *(short8*)&B16[0][boff];
                    short8 blo = *(short8*)&B16[1][boff];
                    acc[nt] = __builtin_amdgcn_mfma_f32_16x16x32_bf16(ahi, bhi, acc[nt], 0, 0, 0);
                    acc[nt] = __builtin_amdgcn_mfma_f32_16x16x32_bf16(ahi, blo, acc[nt], 0, 0, 0);
                    acc[nt] = __builtin_amdgcn_mfma_f32_16x16x32_bf16(alo, bhi, acc[nt], 0, 0, 0);
                }
            }
            __syncthreads();
        }
    }
    // epilogue: relu(acc + bias) -> X248[:, (d-128) .. (d-128)+62)
    const int mloc = wv * 16 + (lane >> 4) * 4;
    #pragma unroll
    for (int nt = 0; nt < 4; ++nt) {
        int c = nt * 16 + (lane & 15);
        #pragma unroll
        for (int rg = 0; rg < 4; ++rg) {
            int m = mloc + rg;
            if (m < NODES && c < OUT_DIM) {
                float v = fmaxf(acc[nt][rg] + bias_s[c], 0.f);
                X248[(size_t)(g * NODES + m) * ACOLS + (d - IN_DIM) + c] = v;
            }
        }
    }
}

// ---------------------------------------------------------------------------
// Head GEMM1, bf16 MFMA, split-K=4: H1 += feats @ Wh1. feats[b][k] is the
// CONTIGUOUS row X248[b*15376 + k] (fp32, converted to bf16 while staging).
// Grid (32, 8, 4) = 1024 blocks. H1 pre-init'd to bias; atomic fp32 epilogue.
// ---------------------------------------------------------------------------
__global__ __launch_bounds__(256) void gemm_head1_mfma(
    const float* __restrict__ F32, const unsigned short* __restrict__ WT1,
    float* __restrict__ H1)
{
    __shared__ __align__(16) unsigned short A16[64 * BSTR];
    __shared__ __align__(16) unsigned short B16[64 * BSTR];
    const int tid  = threadIdx.x;
    const int lane = tid & 63;
    const int wv   = tid >> 6;
    const int bm = blockIdx.x, bnb = blockIdx.y, s = blockIdx.z;
    const int c0 = (481 * s) / 4, c1 = (481 * (s + 1)) / 4;
    const int mr = tid >> 2, kg = (tid & 3) * 8;

    f32x4 acc[4];
    acc[0] = (f32x4){0.f, 0.f, 0.f, 0.f};
    acc[1] = (f32x4){0.f, 0.f, 0.f, 0.f};
    acc[2] = (f32x4){0.f, 0.f, 0.f, 0.f};
    acc[3] = (f32x4){0.f, 0.f, 0.f, 0.f};

    for (int ch = c0; ch < c1; ++ch) {
        const int k = ch * 32 + kg;
        short8 av = {0, 0, 0, 0, 0, 0, 0, 0};
        short8 bv = {0, 0, 0, 0, 0, 0, 0, 0};
        if (k + 8 <= FEAT) {   // FEAT % 8 == 0 -> all-or-nothing groups
            const float4* p = (const float4*)&F32[(size_t)(bm * 64 + mr) * FEAT + k];
            float4 u0 = p[0], u1 = p[1];
            av[0] = (short)f2bf(u0.x); av[1] = (short)f2bf(u0.y);
            av[2] = (short)f2bf(u0.z); av[3] = (short)f2bf(u0.w);
            av[4] = (short)f2bf(u1.x); av[5] = (short)f2bf(u1.y);
            av[6] = (short)f2bf(u1.z); av[7] = (short)f2bf(u1.w);
            bv = *(const short8*)&WT1[(size_t)(bnb * 64 + mr) * FEAT + k];
        }
        *(short8*)&A16[mr * BSTR + kg] = av;
        *(short8*)&B16[mr * BSTR + kg] = bv;
        __syncthreads();
        short8 af = *(short8*)&A16[(wv * 16 + (lane & 15)) * BSTR + (lane >> 4) * 8];
        #pragma unroll
        for (int nt = 0; nt < 4; ++nt) {
            short8 bf = *(short8*)&B16[(nt * 16 + (lane & 15)) * BSTR + (lane >> 4) * 8];
            acc[nt] = __builtin_amdgcn_mfma_f32_16x16x32_bf16(af, bf, acc[nt], 0, 0, 0);
        }
        __syncthreads();
    }
    const int m0 = bm * 64 + wv * 16 + (lane >> 4) * 4;
    #pragma unroll
    for (int nt = 0; nt < 4; ++nt) {
        int c = bnb * 64 + nt * 16 + (lane & 15);
        #pragma unroll
        for (int rg = 0; rg < 4; ++rg)
            atomicAdd(&H1[(size_t)(m0 + rg) * LIN1 + c], acc[nt][rg]);
    }
}

// ---------------------------------------------------------------------------
// GEMM2 fp32 (split-K=4): H2 += H1[2048,512] @ Wh2. (0.54 GFLOP - cheap)
// ---------------------------------------------------------------------------
#define ACC16(av, bv) do {                              \
    acc[0][0] = fmaf((av).x, (bv).x, acc[0][0]);        \
    acc[0][1] = fmaf((av).x, (bv).y, acc[0][1]);        \
    acc[0][2] = fmaf((av).x, (bv).z, acc[0][2]);        \
    acc[0][3] = fmaf((av).x, (bv).w, acc[0][3]);        \
    acc[1][0] = fmaf((av).y, (bv).x, acc[1][0]);        \
    acc[1][1] = fmaf((av).y, (bv).y, acc[1][1]);        \
    acc[1][2] = fmaf((av).y, (bv).z, acc[1][2]);        \
    acc[1][3] = fmaf((av).y, (bv).w, acc[1][3]);        \
    acc[2][0] = fmaf((av).z, (bv).x, acc[2][0]);        \
    acc[2][1] = fmaf((av).z, (bv).y, acc[2][1]);        \
    acc[2][2] = fmaf((av).z, (bv).z, acc[2][2]);        \
    acc[2][3] = fmaf((av).z, (bv).w, acc[2][3]);        \
    acc[3][0] = fmaf((av).w, (bv).x, acc[3][0]);        \
    acc[3][1] = fmaf((av).w, (bv).y, acc[3][1]);        \
    acc[3][2] = fmaf((av).w, (bv).z, acc[3][2]);        \
    acc[3][3] = fmaf((av).w, (bv).w, acc[3][3]);        \
} while (0)

#define SPLIT2 4
__global__ __launch_bounds__(256) void gemm2_kernel(
    const float* __restrict__ A, const float* __restrict__ B,
    float* __restrict__ C)
{
    __shared__ __align__(16) float As[16 * 72];
    __shared__ __align__(16) float Bs[16 * 64];
    const int bm = blockIdx.x, bnb = blockIdx.y, s = blockIdx.z;
    const int tid = threadIdx.x;
    const int ty4 = (tid >> 4) * 4;
    const int tx4 = (tid & 15) * 4;
    const int kbeg = s * (LIN1 / SPLIT2);
    const int kend = kbeg + LIN1 / SPLIT2;
    float acc[4][4] = {};
    for (int k0 = kbeg; k0 < kend; k0 += 16) {
        for (int i = tid; i < 1024; i += 256) {
            int m = i >> 4, kt = i & 15;
            As[kt * 72 + m] = A[(size_t)(bm * 64 + m) * LIN1 + k0 + kt];
        }
        for (int i = tid; i < 1024; i += 256) {
            int kt = i >> 6, c = i & 63;
            Bs[kt * 64 + c] = B[(size_t)(k0 + kt) * LIN2 + bnb * 64 + c];
        }
        __syncthreads();
        #pragma unroll
        for (int kt = 0; kt < 16; ++kt) {
            const float4 av = *(const float4*)&As[kt * 72 + ty4];
            const float4 bv = *(const float4*)&Bs[kt * 64 + tx4];
            ACC16(av, bv);
        }
        __syncthreads();
    }
    const int b = bm * 64 + ty4, c = bnb * 64 + tx4;
    #pragma unroll
    for (int i = 0; i < 4; ++i)
        #pragma unroll
        for (int j = 0; j < 4; ++j)
            atomicAdd(&C[(size_t)(b + i) * LIN2 + c + j], acc[i][j]);
}

// ---------------------------------------------------------------------------
// BatchNorm (training stats, biased var) + ReLU, in place.
// ---------------------------------------------------------------------------
__global__ __launch_bounds__(256) void bn_relu_kernel(
    float* __restrict__ H, int C,
    const float* __restrict__ gamma, const float* __restrict__ beta)
{
    const int c  = blockIdx.x * 16 + (threadIdx.x & 15);
    const int rt = threadIdx.x >> 4;
    const int ct = threadIdx.x & 15;
    float s = 0.f, s2 = 0.f;
    for (int r = rt; r < BATCH; r += 16) {
        float v = H[(size_t)r * C + c];
        s += v; s2 += v * v;
    }
    __shared__ float Ss[16][16], S2s[16][16], sc_s[16], sh_s[16];
    Ss[rt][ct] = s; S2s[rt][ct] = s2;
    __syncthreads();
    if (rt == 0) {
        float ts = 0.f, ts2 = 0.f;
        #pragma unroll
        for (int i = 0; i < 16; ++i) { ts += Ss[i][ct]; ts2 += S2s[i][ct]; }
        float m   = ts * (1.f / BATCH);
        float var = ts2 * (1.f / BATCH) - m * m;
        float sc  = gamma[c] * rsqrtf(var + BN_EPS);
        sc_s[ct] = sc;
        sh_s[ct] = beta[c] - m * sc;
    }
    __syncthreads();
    const float sc = sc_s[ct], sh = sh_s[ct];
    for (int r = rt; r < BATCH; r += 16) {
        float v = H[(size_t)r * C + c];
        H[(size_t)r * C + c] = fmaxf(fmaf(v, sc, sh), 0.f);
    }
}

// ---------------------------------------------------------------------------
// Final: logits = H2 @ Wh3 + bh3, softmax over 3 classes.
// ---------------------------------------------------------------------------
__global__ __launch_bounds__(256) void final_kernel(
    const float* __restrict__ H2, const float* __restrict__ Wh3,
    const float* __restrict__ bh3, float* __restrict__ out)
{
    __shared__ float Ws[LIN2 * NCLS];
    __shared__ float bs[NCLS];
    const int tid = threadIdx.x;
    for (int i = tid; i < LIN2 * NCLS; i += 256) Ws[i] = Wh3[i];
    if (tid < NCLS) bs[tid] = bh3[tid];
    __syncthreads();
    const int r = blockIdx.x * 256 + tid;
    float a0 = bs[0], a1 = bs[1], a2 = bs[2];
    const float4* row = (const float4*)&H2[(size_t)r * LIN2];
    for (int k4 = 0; k4 < LIN2 / 4; ++k4) {
        float4 h = row[k4];
        int k = k4 * 4;
        a0 = fmaf(h.x, Ws[(k + 0) * 3 + 0], a0);
        a1 = fmaf(h.x, Ws[(k + 0) * 3 + 1], a1);
        a2 = fmaf(h.x, Ws[(k + 0) * 3 + 2], a2);
        a0 = fmaf(h.y, Ws[(k + 1) * 3 + 0], a0);
        a1 = fmaf(h.y, Ws[(k + 1) * 3 + 1], a1);
        a2 = fmaf(h.y, Ws[(k + 1) * 3 + 2], a2);
        a0 = fmaf(h.z, Ws[(k + 2) * 3 + 0], a0);
        a1 = fmaf(h.z, Ws[(k + 2) * 3 + 1], a1);
        a2 = fmaf(h.z, Ws[(k + 2) * 3 + 2], a2);
        a0 = fmaf(h.w, Ws[(k + 3) * 3 + 0], a0);
        a1 = fmaf(h.w, Ws[(k + 3) * 3 + 1], a1);
        a2 = fmaf(h.w, Ws[(k + 3) * 3 + 2], a2);
    }
    float mx = fmaxf(a0, fmaxf(a1, a2));
    float e0 = expf(a0 - mx), e1 = expf(a1 - mx), e2 = expf(a2 - mx);
    float inv = 1.f / (e0 + e1 + e2);
    out[r * 3 + 0] = e0 * inv;
    out[r * 3 + 1] = e1 * inv;
    out[r * 3 + 2] = e2 * inv;
}

// ---------------------------------------------------------------------------
extern "C" void kernel_launch(void* const* d_in, const int* in_sizes, int n_in,
                              void* d_out, int out_size, void* d_ws, size_t ws_size,
                              hipStream_t stream)
{
    const float* x   = (const float*)d_in[0];
    const int*   ei  = (const int*)  d_in[1];
    const float* W1  = (const float*)d_in[2];
    const float* b1  = (const float*)d_in[3];
    const float* W2  = (const float*)d_in[4];
    const float* b2  = (const float*)d_in[5];
    const float* W3  = (const float*)d_in[6];
    const float* b3  = (const float*)d_in[7];
    const float* W4  = (const float*)d_in[8];
    const float* b4  = (const float*)d_in[9];
    const float* Wh1 = (const float*)d_in[10];
    const float* bh1 = (const float*)d_in[11];
    const float* g1  = (const float*)d_in[12];
    const float* be1 = (const float*)d_in[13];
    const float* Wh2 = (const float*)d_in[14];
    const float* bh2 = (const float*)d_in[15];
    const float* g2  = (const float*)d_in[16];
    const float* be2 = (const float*)d_in[17];
    const float* Wh3 = (const float*)d_in[18];
    const float* bh3 = (const float*)d_in[19];
    float* out = (float*)d_out;

    // workspace layout -- TOTAL 148,701,184 B (~142 MB; R2's proven 197 MB ok,
    // R3's 264 MB crashed => keep well under):
    char* ws = (char*)d_ws;
    int*   ell_ci = (int*)(ws + 0);                                  //   6144
    float* ell_cv = (float*)(ws + 8192);                             //   6144
    unsigned short* WT1c = (unsigned short*)(ws + 16384);            // 98304   (Kcat 384)
    unsigned short* WT2c = (unsigned short*)(ws + 114688);           // 147456  (Kcat 576)
    unsigned short* WT3c = (unsigned short*)(ws + 262144);           // 196608  (Kcat 768)
    unsigned short* WT4c = (unsigned short*)(ws + 458752);           // 245760  (Kcat 960)
    unsigned short* Wh1T = (unsigned short*)(ws + 704512);           // 15,745,024
    float* X248 = (float*)(ws + 16449536);                           // 125,960,192
    float* H1   = (float*)(ws + 142409728);                          // 4,194,304
    float* H2   = (float*)(ws + 146604032);                          // 2,097,152

    const int E   = in_sizes[1] / 2;   // 1,015,808
    const int epg = E / BATCH;         // 496 edges of graph 0

    build_L<<<1, 64, 0, stream>>>(ei, E, epg, ell_ci, ell_cv);

    conv_wcheb<<<(64 * 384 + 255) / 256, 256, 0, stream>>>(W1, WT1c, 128, 128);
    conv_wcheb<<<(64 * 576 + 255) / 256, 256, 0, stream>>>(W2, WT2c, 190, 192);
    conv_wcheb<<<(64 * 768 + 255) / 256, 256, 0, stream>>>(W3, WT3c, 252, 256);
    conv_wcheb<<<(64 * 960 + 255) / 256, 256, 0, stream>>>(W4, WT4c, 314, 320);
    transpose_wh1<<<dim3(481, 16), 256, 0, stream>>>(Wh1, Wh1T);

    cheb_mfma<<<BATCH, 256, 0, stream>>>(x, X248, WT1c, b1, ell_ci, ell_cv, 128, 128);
    cheb_mfma<<<BATCH, 256, 0, stream>>>(x, X248, WT2c, b2, ell_ci, ell_cv, 190, 192);
    cheb_mfma<<<BATCH, 256, 0, stream>>>(x, X248, WT3c, b3, ell_ci, ell_cv, 252, 256);
    cheb_mfma<<<BATCH, 256, 0, stream>>>(x, X248, WT4c, b4, ell_ci, ell_cv, 314, 320);

    init_bias<<<(BATCH * LIN1 / 4 + 255) / 256, 256, 0, stream>>>(H1, bh1, LIN1 / 4 - 1, BATCH * LIN1 / 4);
    gemm_head1_mfma<<<dim3(32, 8, 4), 256, 0, stream>>>(X248, Wh1T, H1);
    bn_relu_kernel<<<LIN1 / 16, 256, 0, stream>>>(H1, LIN1, g1, be1);

    init_bias<<<(BATCH * LIN2 / 4 + 255) / 256, 256, 0, stream>>>(H2, bh2, LIN2 / 4 - 1, BATCH * LIN2 / 4);
    gemm2_kernel<<<dim3(32, 4, SPLIT2), 256, 0, stream>>>(H1, Wh2, H2);
    bn_relu_kernel<<<LIN2 / 16, 256, 0, stream>>>(H2, LIN2, g2, be2);

    final_kernel<<<BATCH / 256, 256, 0, stream>>>(H2, Wh3, bh3, out);
}